// Round 8
// baseline (5523.404 us; speedup 1.0000x reference)
//
#include <hip/hip_runtime.h>

typedef unsigned short u16;
typedef unsigned int   u32;
typedef unsigned long long u64;
typedef __attribute__((ext_vector_type(8)))  short  short8v;   // 8 x bf16 (as i16)
typedef __attribute__((ext_vector_type(4)))  float  f32x4;
typedef __attribute__((ext_vector_type(16))) float  f32x16;
typedef __attribute__((ext_vector_type(4)))  unsigned short ushort4v;
typedef __attribute__((ext_vector_type(4)))  u32 u32x4;

#define B_   32
#define T_   512
#define D_   1024
#define N4_  4096

// ---- workspace layout (bytes) ----
#define OFF_XN   0ull                 // xn bf16   [32*512*1024]      33554432
#define OFF_ZX   33554432ull          // Zx bf16   [512][32][1024][4] 134217728  (gate-interleaved)
#define OFF_KT   167772160ull         // kernel^T bf16 [4096][1024]    8388608  (reused as h_last after GEMM)
#define OFF_RT   176160768ull         // recurrent^T bf16 [4096][1024] 8388608
#define OFF_HB   184549376ull         // h double buffer bf16 2*[32][1024] = 131072
#define OFF_FLG  184680448ull         // flags: 32 x 64B-strided u32

__device__ inline u16 f2bf(float f) {
  union { float f; u32 u; } x; x.f = f;
  u32 r = x.u + 0x7FFFu + ((x.u >> 16) & 1u);   // RNE
  return (u16)(r >> 16);
}
__device__ inline float bf2f(u16 h) {
  union { u32 u; float f; } x; x.u = ((u32)h) << 16; return x.f;
}
__device__ inline float sigm(float x) { return 1.f / (1.f + __expf(-x)); }
__device__ inline float tanh_fast(float x) {
  float e = __expf(2.f * x);
  return 1.f - 2.f / (e + 1.f);
}

// ---------------- init: zero h buffers + flags ----------------
__global__ __launch_bounds__(256) void init_kernel(u32* hbuf, u32* flags) {
  int i = blockIdx.x * 256 + threadIdx.x;
  if (i < 32768) hbuf[i] = 0u;       // both parities: 2*32*1024 bf16 = 32768 dwords
  if (i < 32)    flags[i * 16] = 0u;
}

// ---------------- LN1: x fp32 -> xn bf16 ----------------
__global__ __launch_bounds__(256) void ln1_kernel(const float* __restrict__ x,
    const float* __restrict__ gam, const float* __restrict__ bet, u16* __restrict__ xn) {
  int row = blockIdx.x; int tid = threadIdx.x;
  const float* xr = x + (size_t)row * D_;
  float4 v = *(const float4*)(xr + tid * 4);
  float s  = v.x + v.y + v.z + v.w;
  float ss = v.x*v.x + v.y*v.y + v.z*v.z + v.w*v.w;
  #pragma unroll
  for (int o = 32; o > 0; o >>= 1) { s += __shfl_down(s, o); ss += __shfl_down(ss, o); }
  __shared__ float red[8];
  int w = tid >> 6, l = tid & 63;
  if (l == 0) { red[w] = s; red[4 + w] = ss; }
  __syncthreads();
  s  = red[0] + red[1] + red[2] + red[3];
  ss = red[4] + red[5] + red[6] + red[7];
  float mean = s * (1.f / D_);
  float var  = ss * (1.f / D_) - mean * mean;
  float rstd = rsqrtf(var + 1e-3f);
  float4 g = *(const float4*)(gam + tid * 4);
  float4 b = *(const float4*)(bet + tid * 4);
  ushort4v o4;
  o4.x = f2bf((v.x - mean) * rstd * g.x + b.x);
  o4.y = f2bf((v.y - mean) * rstd * g.y + b.y);
  o4.z = f2bf((v.z - mean) * rstd * g.z + b.z);
  o4.w = f2bf((v.w - mean) * rstd * g.w + b.w);
  *(ushort4v*)(xn + (size_t)row * D_ + tid * 4) = o4;
}

// ---------------- transpose [1024][4096] fp32 -> [4096][1024] bf16 ----------------
__global__ __launch_bounds__(256) void transpose_bf16(const float* __restrict__ W, u16* __restrict__ WT) {
  __shared__ float tile[32][33];
  int c0 = blockIdx.x * 32, r0 = blockIdx.y * 32;
  int tx = threadIdx.x, ty = threadIdx.y;
  #pragma unroll
  for (int i = ty; i < 32; i += 8)
    tile[i][tx] = W[(size_t)(r0 + i) * N4_ + c0 + tx];
  __syncthreads();
  #pragma unroll
  for (int i = ty; i < 32; i += 8)
    WT[(size_t)(c0 + i) * D_ + r0 + tx] = f2bf(tile[tx][i]);
}

// ---------------- GEMM: Zx = xn @ kernel + bias  (gate-interleaved output) ----------------
__global__ __launch_bounds__(256) void gemm_xk(const u16* __restrict__ A, const u16* __restrict__ Bt,
    const float* __restrict__ bias, u16* __restrict__ Zx) {
  __shared__ u16 As[128 * 32];
  __shared__ u16 Bs[128 * 32];
  int tid = threadIdx.x;
  int bm = blockIdx.x >> 5, bn = blockIdx.x & 31;
  int w = tid >> 6, l = tid & 63;
  int srow = tid >> 2, sk = (tid & 3) * 8;        // staging: row j*64+srow, k = sk..sk+8
  const u16* Ag = A  + (size_t)(bm * 128 + srow) * D_ + sk;
  const u16* Bg = Bt + (size_t)(bn * 128 + srow) * D_ + sk;
  int sb0 = (srow * 64 + sk * 2)          ^ ((srow & 3) << 4);
  int sb1 = ((srow + 64) * 64 + sk * 2)   ^ ((srow & 3) << 4);
  int wm = w >> 1, wn = w & 1;
  int frow = l & 15, fko = (l >> 4) * 16;         // fragment k byte offset
  f32x4 acc[4][4];
  #pragma unroll
  for (int mi = 0; mi < 4; ++mi)
    #pragma unroll
    for (int ni = 0; ni < 4; ++ni)
      #pragma unroll
      for (int j = 0; j < 4; ++j) acc[mi][ni][j] = 0.f;

  short8v ap0 = *(const short8v*)(Ag);
  short8v ap1 = *(const short8v*)(Ag + 64 * (size_t)D_);
  short8v bp0 = *(const short8v*)(Bg);
  short8v bp1 = *(const short8v*)(Bg + 64 * (size_t)D_);

  for (int kt = 0; kt < 32; ++kt) {
    __syncthreads();
    *(short8v*)((char*)As + sb0) = ap0;
    *(short8v*)((char*)As + sb1) = ap1;
    *(short8v*)((char*)Bs + sb0) = bp0;
    *(short8v*)((char*)Bs + sb1) = bp1;
    __syncthreads();
    if (kt < 31) {
      ap0 = *(const short8v*)(Ag + (kt + 1) * 32);
      ap1 = *(const short8v*)(Ag + 64 * (size_t)D_ + (kt + 1) * 32);
      bp0 = *(const short8v*)(Bg + (kt + 1) * 32);
      bp1 = *(const short8v*)(Bg + 64 * (size_t)D_ + (kt + 1) * 32);
    }
    short8v af[4], bfr[4];
    #pragma unroll
    for (int mi = 0; mi < 4; ++mi) {
      int r = wm * 64 + mi * 16 + frow;
      af[mi] = *(const short8v*)((char*)As + ((r * 64 + fko) ^ ((r & 3) << 4)));
    }
    #pragma unroll
    for (int ni = 0; ni < 4; ++ni) {
      int r = wn * 64 + ni * 16 + frow;
      bfr[ni] = *(const short8v*)((char*)Bs + ((r * 64 + fko) ^ ((r & 3) << 4)));
    }
    #pragma unroll
    for (int mi = 0; mi < 4; ++mi)
      #pragma unroll
      for (int ni = 0; ni < 4; ++ni)
        acc[mi][ni] = __builtin_amdgcn_mfma_f32_16x16x32_bf16(af[mi], bfr[ni], acc[mi][ni], 0, 0, 0);
  }
  // epilogue: +bias, bf16, remap rows to [t][b] and cols to [unit][gate]
  #pragma unroll
  for (int mi = 0; mi < 4; ++mi) {
    #pragma unroll
    for (int ni = 0; ni < 4; ++ni) {
      int col = bn * 128 + wn * 64 + ni * 16 + (l & 15);
      float bv = bias[col];
      int colp = ((col & 1023) << 2) | (col >> 10);   // gate-interleaved
      #pragma unroll
      for (int j = 0; j < 4; ++j) {
        int row = bm * 128 + wm * 64 + mi * 16 + (l >> 4) * 4 + j;
        int zrow = (row & 511) * 32 + (row >> 9);
        Zx[(size_t)zrow * N4_ + colp] = f2bf(acc[mi][ni][j] + bv);
      }
    }
  }
}

// ---------------- persistent LSTM scan ----------------
// 32 WGs x 1024 thr (16 waves = 4 K-splits x 4 gates). WG owns units [wg*32, wg*32+32).
// Exchange: wave0-only flag poll + raw s_barrier release; 16B coherent h loads.
// R-slice (256KB/WG/step, L2-resident) loads are issued via ASM VOLATILE at the top
// of each iteration — plain C++ loads get sunk into the K-loop by the compiler
// (R5/R7 post-mortems: VGPR stuck at 64), serializing ~1.7us of L2 traffic after
// the exchange. asm volatile + memory clobber is immovable, so the R traffic
// overlaps the poll + h-load window and the K-loop runs from registers.
__global__ __launch_bounds__(1024, 4) void lstm_scan(const u16* __restrict__ Zx,
    const u16* __restrict__ RT, u16* hbuf, float* h_last, u32* flags) {
  __shared__ u16   h_lds[B_ * D_];           // 64 KB, XOR-swizzled rows
  __shared__ float z_lds[128 * 136];         // 69.6 KB: [ks*32+row][stride 136]
  int tid = threadIdx.x;
  int wg = blockIdx.x;
  int w = tid >> 6, l = tid & 63;
  int ks = w >> 2, cg = w & 3;               // K-range ks*256..+256, gate cg

  // per-lane R^T fragment base (16 x 16B per step)
  const u16* Rp = RT + (size_t)(cg * 1024 + wg * 32 + (l & 31)) * D_
                + ks * 256 + (l >> 5) * 8;

  // A-fragment addressing (h in LDS, swizzled)
  int arow = l & 31;
  int abase = arow * 2048 + (ks * 256 + (l >> 5) * 8) * 2;
  int asw = (arow & 7) << 4;
  // gate cell: (grow, gu)
  int grow = tid >> 5, gu = tid & 31;
  const u16* zx_p = Zx + (size_t)grow * N4_ + (wg * 32 + gu) * 4;
  int hoff = grow * D_ + wg * 32 + gu;
  float c = 0.f;
  const u32* fp = flags + (size_t)(l & 31) * 16;

  #pragma unroll 1
  for (int t = 0; t < T_; ++t) {
    // (1) issue this step's R-fragment loads as immovable asm — they complete
    //     under the exchange window, not inside the K-loop
    short8v bfrag[16];
    #pragma unroll
    for (int kt = 0; kt < 16; ++kt)
      asm volatile("global_load_dwordx4 %0, %1, off offset:%2"
                   : "=v"(bfrag[kt]) : "v"(Rp), "i"(kt * 32) : "memory");
    // (2) Zx prefetch (4 gate pre-activations), also immovable
    u64 zq;
    {
      const u16* zp = zx_p + (size_t)t * B_ * N4_;
      asm volatile("global_load_dwordx2 %0, %1, off"
                   : "=v"(zq) : "v"(zp) : "memory");
    }

    // (3) wave0 polls the 32 per-WG flags; raw s_barrier releases the other 15 waves
    if (w == 0) {
      while (true) {
        u32 f = __hip_atomic_load(fp, __ATOMIC_RELAXED, __HIP_MEMORY_SCOPE_AGENT);
        if (__all((int)(f >= (u32)t))) break;
      }
    }
    __builtin_amdgcn_s_barrier();
    __builtin_amdgcn_sched_barrier(0);

    // (4) bulk-load h: 4 x 16B coherent loads per thread (sc0 sc1 bypass stale L1/L2)
    const char* hbp = (const char*)hbuf + (size_t)(t & 1) * 65536;
    u32x4 hv[4];
    #pragma unroll
    for (int j = 0; j < 4; ++j) {
      const char* p = hbp + j * 16384 + tid * 16;
      asm volatile("global_load_dwordx4 %0, %1, off sc0 sc1"
                   : "=&v"(hv[j]) : "v"(p) : "memory");
    }
    asm volatile("s_waitcnt vmcnt(0)" ::: "memory");   // drains h + R + Zx loads
    __builtin_amdgcn_sched_barrier(0);
    #pragma unroll
    for (int j = 0; j < 4; ++j) {
      int byte = j * 16384 + tid * 16;
      int row = byte >> 11;
      *(u32x4*)((char*)h_lds + (byte ^ ((row & 7) << 4))) = hv[j];
    }
    __syncthreads();

    // (5) K-loop: 16 x (ds_read_b128 + mfma 32x32x16), B operands in registers
    f32x16 acc;
    #pragma unroll
    for (int i = 0; i < 16; ++i) acc[i] = 0.f;
    #pragma unroll
    for (int kt = 0; kt < 16; ++kt) {
      short8v a = *(const short8v*)((const char*)h_lds + ((abase + kt * 32) ^ asw));
      acc = __builtin_amdgcn_mfma_f32_32x32x16_bf16(a, bfrag[kt], acc, 0, 0, 0);
    }
    // write K-partials: D layout row=(r&3)+8*(r>>2)+4*(lane>>5), col=lane&31
    #pragma unroll
    for (int r = 0; r < 16; ++r) {
      int rowD = (r & 3) + 8 * (r >> 2) + 4 * (l >> 5);
      z_lds[(ks * 32 + rowD) * 136 + cg * 32 + (l & 31)] = acc[r];
    }
    __syncthreads();

    // (6) gates: one cell per thread
    float z0 = bf2f((u16)(zq        & 0xFFFFu));
    float z1 = bf2f((u16)((zq >> 16) & 0xFFFFu));
    float z2 = bf2f((u16)((zq >> 32) & 0xFFFFu));
    float z3 = bf2f((u16)((zq >> 48) & 0xFFFFu));
    #pragma unroll
    for (int kss = 0; kss < 4; ++kss) {
      const float* zr = &z_lds[(kss * 32 + grow) * 136 + gu];
      z0 += zr[0]; z1 += zr[32]; z2 += zr[64]; z3 += zr[96];
    }
    float cn = sigm(z1) * c + sigm(z0) * tanh_fast(z2);
    float hn = sigm(z3) * tanh_fast(cn);
    c = cn;

    // (7) publish h (pair lanes -> u32 agent-scope store)
    u32 hw = (u32)f2bf(hn);
    u32 nb = __shfl_down(hw, 1);
    if (!(gu & 1)) {
      u32* dst = (u32*)(hbuf + (size_t)((t + 1) & 1) * (B_ * D_) + hoff);
      __hip_atomic_store(dst, hw | (nb << 16), __ATOMIC_RELAXED, __HIP_MEMORY_SCOPE_AGENT);
    }
    if (t == T_ - 1) h_last[hoff] = hn;
    // drain all waves' stores, then publish the flag
    __syncthreads();
    if (tid == 0)
      __hip_atomic_store(flags + (size_t)wg * 16, (u32)(t + 1),
                         __ATOMIC_RELAXED, __HIP_MEMORY_SCOPE_AGENT);
  }
}

// ---------------- LN2: out = LN(xn + h_last) fp32 ----------------
__global__ __launch_bounds__(256) void ln2_kernel(const u16* __restrict__ xn,
    const float* __restrict__ h_last, const float* __restrict__ gam,
    const float* __restrict__ bet, float* __restrict__ out) {
  int row = blockIdx.x; int tid = threadIdx.x;
  int bi = row >> 9;
  ushort4v xv = *(const ushort4v*)(xn + (size_t)row * D_ + tid * 4);
  float4 hv = *(const float4*)(h_last + (size_t)bi * D_ + tid * 4);
  float s0 = bf2f(xv.x) + hv.x;
  float s1 = bf2f(xv.y) + hv.y;
  float s2 = bf2f(xv.z) + hv.z;
  float s3 = bf2f(xv.w) + hv.w;
  float s = s0 + s1 + s2 + s3;
  float ss = s0*s0 + s1*s1 + s2*s2 + s3*s3;
  #pragma unroll
  for (int o = 32; o > 0; o >>= 1) { s += __shfl_down(s, o); ss += __shfl_down(ss, o); }
  __shared__ float red[8];
  int w = tid >> 6, l = tid & 63;
  if (l == 0) { red[w] = s; red[4 + w] = ss; }
  __syncthreads();
  s  = red[0] + red[1] + red[2] + red[3];
  ss = red[4] + red[5] + red[6] + red[7];
  float mean = s * (1.f / D_);
  float var  = ss * (1.f / D_) - mean * mean;
  float rstd = rsqrtf(var + 1e-3f);
  float4 g = *(const float4*)(gam + tid * 4);
  float4 b = *(const float4*)(bet + tid * 4);
  float4 o4;
  o4.x = (s0 - mean) * rstd * g.x + b.x;
  o4.y = (s1 - mean) * rstd * g.y + b.y;
  o4.z = (s2 - mean) * rstd * g.z + b.z;
  o4.w = (s3 - mean) * rstd * g.w + b.w;
  *(float4*)(out + (size_t)row * D_ + tid * 4) = o4;
}

extern "C" void kernel_launch(void* const* d_in, const int* in_sizes, int n_in,
                              void* d_out, int out_size, void* d_ws, size_t ws_size,
                              hipStream_t stream) {
  const float* x    = (const float*)d_in[0];
  const float* g1   = (const float*)d_in[1];
  const float* b1   = (const float*)d_in[2];
  const float* Wk   = (const float*)d_in[3];
  const float* Wr   = (const float*)d_in[4];
  const float* bias = (const float*)d_in[5];
  const float* g2   = (const float*)d_in[6];
  const float* b2   = (const float*)d_in[7];
  char* ws = (char*)d_ws;
  u16* xn    = (u16*)(ws + OFF_XN);
  u16* Zx    = (u16*)(ws + OFF_ZX);
  u16* KT    = (u16*)(ws + OFF_KT);
  u16* RT    = (u16*)(ws + OFF_RT);
  u16* hbuf  = (u16*)(ws + OFF_HB);
  u32* flg   = (u32*)(ws + OFF_FLG);
  float* hl  = (float*)(ws + OFF_KT);    // aliases KT (dead after gemm_xk)
  float* out = (float*)d_out;

  init_kernel<<<128, 256, 0, stream>>>((u32*)hbuf, flg);
  ln1_kernel<<<B_ * T_, 256, 0, stream>>>(x, g1, b1, xn);
  transpose_bf16<<<dim3(128, 32), dim3(32, 8), 0, stream>>>(Wk, KT);
  transpose_bf16<<<dim3(128, 32), dim3(32, 8), 0, stream>>>(Wr, RT);
  gemm_xk<<<4096, 256, 0, stream>>>(xn, KT, bias, Zx);
  lstm_scan<<<32, 1024, 0, stream>>>(Zx, RT, hbuf, hl, flg);
  ln2_kernel<<<B_ * T_, 256, 0, stream>>>(xn, hl, g2, b2, out);
}

// Round 9
// 2309.399 us; speedup vs baseline: 2.3917x; 2.3917x over previous
//
#include <hip/hip_runtime.h>

typedef unsigned short u16;
typedef unsigned int   u32;
typedef unsigned long long u64;
typedef __attribute__((ext_vector_type(8)))  short  short8v;   // 8 x bf16 (as i16)
typedef __attribute__((ext_vector_type(4)))  float  f32x4;
typedef __attribute__((ext_vector_type(16))) float  f32x16;
typedef __attribute__((ext_vector_type(4)))  unsigned short ushort4v;
typedef __attribute__((ext_vector_type(4)))  u32 u32x4;

#define B_   32
#define T_   512
#define D_   1024
#define N4_  4096

// ---- workspace layout (bytes) ----
#define OFF_XN   0ull                 // xn bf16   [32*512*1024]      33554432
#define OFF_ZX   33554432ull          // Zx bf16   [512][32][1024][4] 134217728  (gate-interleaved)
#define OFF_KT   167772160ull         // kernel^T bf16 [4096][1024]    8388608  (reused as h_last after GEMM)
#define OFF_RT   176160768ull         // recurrent^T bf16 [4096][1024] 8388608
#define OFF_HB   184549376ull         // h double buffer bf16 2*[32][1024] = 131072
#define OFF_FLG  184680448ull         // flags: 32 x 64B-strided u32

__device__ inline u16 f2bf(float f) {
  union { float f; u32 u; } x; x.f = f;
  u32 r = x.u + 0x7FFFu + ((x.u >> 16) & 1u);   // RNE
  return (u16)(r >> 16);
}
__device__ inline float bf2f(u16 h) {
  union { u32 u; float f; } x; x.u = ((u32)h) << 16; return x.f;
}
__device__ inline float sigm(float x) { return 1.f / (1.f + __expf(-x)); }
__device__ inline float tanh_fast(float x) {
  float e = __expf(2.f * x);
  return 1.f - 2.f / (e + 1.f);
}

// ---------------- init: zero h buffers + flags ----------------
__global__ __launch_bounds__(256) void init_kernel(u32* hbuf, u32* flags) {
  int i = blockIdx.x * 256 + threadIdx.x;
  if (i < 32768) hbuf[i] = 0u;       // both parities: 2*32*1024 bf16 = 32768 dwords
  if (i < 32)    flags[i * 16] = 0u;
}

// ---------------- LN1: x fp32 -> xn bf16 ----------------
__global__ __launch_bounds__(256) void ln1_kernel(const float* __restrict__ x,
    const float* __restrict__ gam, const float* __restrict__ bet, u16* __restrict__ xn) {
  int row = blockIdx.x; int tid = threadIdx.x;
  const float* xr = x + (size_t)row * D_;
  float4 v = *(const float4*)(xr + tid * 4);
  float s  = v.x + v.y + v.z + v.w;
  float ss = v.x*v.x + v.y*v.y + v.z*v.z + v.w*v.w;
  #pragma unroll
  for (int o = 32; o > 0; o >>= 1) { s += __shfl_down(s, o); ss += __shfl_down(ss, o); }
  __shared__ float red[8];
  int w = tid >> 6, l = tid & 63;
  if (l == 0) { red[w] = s; red[4 + w] = ss; }
  __syncthreads();
  s  = red[0] + red[1] + red[2] + red[3];
  ss = red[4] + red[5] + red[6] + red[7];
  float mean = s * (1.f / D_);
  float var  = ss * (1.f / D_) - mean * mean;
  float rstd = rsqrtf(var + 1e-3f);
  float4 g = *(const float4*)(gam + tid * 4);
  float4 b = *(const float4*)(bet + tid * 4);
  ushort4v o4;
  o4.x = f2bf((v.x - mean) * rstd * g.x + b.x);
  o4.y = f2bf((v.y - mean) * rstd * g.y + b.y);
  o4.z = f2bf((v.z - mean) * rstd * g.z + b.z);
  o4.w = f2bf((v.w - mean) * rstd * g.w + b.w);
  *(ushort4v*)(xn + (size_t)row * D_ + tid * 4) = o4;
}

// ---------------- transpose [1024][4096] fp32 -> [4096][1024] bf16 ----------------
__global__ __launch_bounds__(256) void transpose_bf16(const float* __restrict__ W, u16* __restrict__ WT) {
  __shared__ float tile[32][33];
  int c0 = blockIdx.x * 32, r0 = blockIdx.y * 32;
  int tx = threadIdx.x, ty = threadIdx.y;
  #pragma unroll
  for (int i = ty; i < 32; i += 8)
    tile[i][tx] = W[(size_t)(r0 + i) * N4_ + c0 + tx];
  __syncthreads();
  #pragma unroll
  for (int i = ty; i < 32; i += 8)
    WT[(size_t)(c0 + i) * D_ + r0 + tx] = f2bf(tile[tx][i]);
}

// ---------------- GEMM: Zx = xn @ kernel + bias  (gate-interleaved output) ----------------
__global__ __launch_bounds__(256) void gemm_xk(const u16* __restrict__ A, const u16* __restrict__ Bt,
    const float* __restrict__ bias, u16* __restrict__ Zx) {
  __shared__ u16 As[128 * 32];
  __shared__ u16 Bs[128 * 32];
  int tid = threadIdx.x;
  int bm = blockIdx.x >> 5, bn = blockIdx.x & 31;
  int w = tid >> 6, l = tid & 63;
  int srow = tid >> 2, sk = (tid & 3) * 8;        // staging: row j*64+srow, k = sk..sk+8
  const u16* Ag = A  + (size_t)(bm * 128 + srow) * D_ + sk;
  const u16* Bg = Bt + (size_t)(bn * 128 + srow) * D_ + sk;
  int sb0 = (srow * 64 + sk * 2)          ^ ((srow & 3) << 4);
  int sb1 = ((srow + 64) * 64 + sk * 2)   ^ ((srow & 3) << 4);
  int wm = w >> 1, wn = w & 1;
  int frow = l & 15, fko = (l >> 4) * 16;         // fragment k byte offset
  f32x4 acc[4][4];
  #pragma unroll
  for (int mi = 0; mi < 4; ++mi)
    #pragma unroll
    for (int ni = 0; ni < 4; ++ni)
      #pragma unroll
      for (int j = 0; j < 4; ++j) acc[mi][ni][j] = 0.f;

  short8v ap0 = *(const short8v*)(Ag);
  short8v ap1 = *(const short8v*)(Ag + 64 * (size_t)D_);
  short8v bp0 = *(const short8v*)(Bg);
  short8v bp1 = *(const short8v*)(Bg + 64 * (size_t)D_);

  for (int kt = 0; kt < 32; ++kt) {
    __syncthreads();
    *(short8v*)((char*)As + sb0) = ap0;
    *(short8v*)((char*)As + sb1) = ap1;
    *(short8v*)((char*)Bs + sb0) = bp0;
    *(short8v*)((char*)Bs + sb1) = bp1;
    __syncthreads();
    if (kt < 31) {
      ap0 = *(const short8v*)(Ag + (kt + 1) * 32);
      ap1 = *(const short8v*)(Ag + 64 * (size_t)D_ + (kt + 1) * 32);
      bp0 = *(const short8v*)(Bg + (kt + 1) * 32);
      bp1 = *(const short8v*)(Bg + 64 * (size_t)D_ + (kt + 1) * 32);
    }
    short8v af[4], bfr[4];
    #pragma unroll
    for (int mi = 0; mi < 4; ++mi) {
      int r = wm * 64 + mi * 16 + frow;
      af[mi] = *(const short8v*)((char*)As + ((r * 64 + fko) ^ ((r & 3) << 4)));
    }
    #pragma unroll
    for (int ni = 0; ni < 4; ++ni) {
      int r = wn * 64 + ni * 16 + frow;
      bfr[ni] = *(const short8v*)((char*)Bs + ((r * 64 + fko) ^ ((r & 3) << 4)));
    }
    #pragma unroll
    for (int mi = 0; mi < 4; ++mi)
      #pragma unroll
      for (int ni = 0; ni < 4; ++ni)
        acc[mi][ni] = __builtin_amdgcn_mfma_f32_16x16x32_bf16(af[mi], bfr[ni], acc[mi][ni], 0, 0, 0);
  }
  // epilogue: +bias, bf16, remap rows to [t][b] and cols to [unit][gate]
  #pragma unroll
  for (int mi = 0; mi < 4; ++mi) {
    #pragma unroll
    for (int ni = 0; ni < 4; ++ni) {
      int col = bn * 128 + wn * 64 + ni * 16 + (l & 15);
      float bv = bias[col];
      int colp = ((col & 1023) << 2) | (col >> 10);   // gate-interleaved
      #pragma unroll
      for (int j = 0; j < 4; ++j) {
        int row = bm * 128 + wm * 64 + mi * 16 + (l >> 4) * 4 + j;
        int zrow = (row & 511) * 32 + (row >> 9);
        Zx[(size_t)zrow * N4_ + colp] = f2bf(acc[mi][ni][j] + bv);
      }
    }
  }
}

// ---------------- persistent LSTM scan ----------------
// 32 WGs x 1024 thr (16 waves = 4 K-splits x 4 gates). WG owns units [wg*32, wg*32+32).
// LDS (135KB) limits to ONE WG/CU = 4 waves/SIMD, so pin occupancy with
// amdgpu_waves_per_eu(4,4): per-wave register budget rises to ~128 and the
// R^T fragments (64 VGPRs) can finally be truly register-resident.
// (R8 post-mortem: under launch_bounds(1024,4) the compiler targeted 8 waves/EU,
// capped VGPRs at 64, and spilled b[16] to scratch — the per-step scratch reload
// was the phantom "R-feed" cost of R4-R8.)
// Exchange: wave0-only flag poll + raw s_barrier release; 16B coherent h loads.
__global__ __launch_bounds__(1024) __attribute__((amdgpu_waves_per_eu(4, 4)))
void lstm_scan(const u16* __restrict__ Zx,
    const u16* __restrict__ RT, u16* hbuf, float* h_last, u32* flags) {
  __shared__ u16   h_lds[B_ * D_];           // 64 KB, XOR-swizzled rows
  __shared__ float z_lds[128 * 136];         // 69.6 KB: [ks*32+row][stride 136]
  int tid = threadIdx.x;
  int wg = blockIdx.x;
  int w = tid >> 6, l = tid & 63;
  int ks = w >> 2, cg = w & 3;               // K-range ks*256..+256, gate cg

  // preload B fragments (R^T) into registers: 16 kt, 64 VGPRs
  short8v b[16];
  {
    const u16* Rp = RT + (size_t)(cg * 1024 + wg * 32 + (l & 31)) * D_
                  + ks * 256 + (l >> 5) * 8;
    #pragma unroll
    for (int kt = 0; kt < 16; ++kt) b[kt] = *(const short8v*)(Rp + kt * 16);
  }
  // pin: volatile redefinition -> not rematerializable from memory inside the loop
  #pragma unroll
  for (int kt = 0; kt < 16; ++kt) asm volatile("" : "+v"(b[kt]));

  // A-fragment addressing (h in LDS, swizzled)
  int arow = l & 31;
  int abase = arow * 2048 + (ks * 256 + (l >> 5) * 8) * 2;
  int asw = (arow & 7) << 4;
  // gate cell: (grow, gu)
  int grow = tid >> 5, gu = tid & 31;
  const u16* zx_p = Zx + (size_t)grow * N4_ + (wg * 32 + gu) * 4;
  int hoff = grow * D_ + wg * 32 + gu;
  float c = 0.f;
  const u32* fp = flags + (size_t)(l & 31) * 16;

  #pragma unroll 1
  for (int t = 0; t < T_; ++t) {
    // prefetch all 4 gate pre-activations (one 8B load; stays in flight across s_barrier)
    u64 zq = *(const u64*)(zx_p + (size_t)t * B_ * N4_);
    __builtin_amdgcn_sched_barrier(0);

    // wave0 polls the 32 per-WG flags; raw s_barrier releases the other 15 waves
    if (w == 0) {
      while (true) {
        u32 f = __hip_atomic_load(fp, __ATOMIC_RELAXED, __HIP_MEMORY_SCOPE_AGENT);
        if (__all((int)(f >= (u32)t))) break;
      }
    }
    __builtin_amdgcn_s_barrier();
    __builtin_amdgcn_sched_barrier(0);

    // bulk-load h: 4 x 16B coherent loads per thread (sc0 sc1 -> bypass stale L1/L2)
    const char* hbp = (const char*)hbuf + (size_t)(t & 1) * 65536;
    u32x4 hv[4];
    #pragma unroll
    for (int j = 0; j < 4; ++j) {
      const char* p = hbp + j * 16384 + tid * 16;
      asm volatile("global_load_dwordx4 %0, %1, off sc0 sc1"
                   : "=&v"(hv[j]) : "v"(p) : "memory");
    }
    asm volatile("s_waitcnt vmcnt(0)" ::: "memory");
    __builtin_amdgcn_sched_barrier(0);
    #pragma unroll
    for (int j = 0; j < 4; ++j) {
      int byte = j * 16384 + tid * 16;
      int row = byte >> 11;
      *(u32x4*)((char*)h_lds + (byte ^ ((row & 7) << 4))) = hv[j];
    }
    __syncthreads();

    // K-loop: 16 x (ds_read_b128 + mfma 32x32x16), register-resident B
    f32x16 acc;
    #pragma unroll
    for (int i = 0; i < 16; ++i) acc[i] = 0.f;
    #pragma unroll
    for (int kt = 0; kt < 16; ++kt) {
      short8v a = *(const short8v*)((const char*)h_lds + ((abase + kt * 32) ^ asw));
      acc = __builtin_amdgcn_mfma_f32_32x32x16_bf16(a, b[kt], acc, 0, 0, 0);
    }
    // write K-partials: D layout row=(r&3)+8*(r>>2)+4*(lane>>5), col=lane&31
    #pragma unroll
    for (int r = 0; r < 16; ++r) {
      int rowD = (r & 3) + 8 * (r >> 2) + 4 * (l >> 5);
      z_lds[(ks * 32 + rowD) * 136 + cg * 32 + (l & 31)] = acc[r];
    }
    __syncthreads();

    // gates: one cell per thread
    float z0 = bf2f((u16)(zq        & 0xFFFFu));
    float z1 = bf2f((u16)((zq >> 16) & 0xFFFFu));
    float z2 = bf2f((u16)((zq >> 32) & 0xFFFFu));
    float z3 = bf2f((u16)((zq >> 48) & 0xFFFFu));
    #pragma unroll
    for (int kss = 0; kss < 4; ++kss) {
      const float* zr = &z_lds[(kss * 32 + grow) * 136 + gu];
      z0 += zr[0]; z1 += zr[32]; z2 += zr[64]; z3 += zr[96];
    }
    float cn = sigm(z1) * c + sigm(z0) * tanh_fast(z2);
    float hn = sigm(z3) * tanh_fast(cn);
    c = cn;

    // publish h (pair lanes -> u32 agent-scope store)
    u32 hw = (u32)f2bf(hn);
    u32 nb = __shfl_down(hw, 1);
    if (!(gu & 1)) {
      u32* dst = (u32*)(hbuf + (size_t)((t + 1) & 1) * (B_ * D_) + hoff);
      __hip_atomic_store(dst, hw | (nb << 16), __ATOMIC_RELAXED, __HIP_MEMORY_SCOPE_AGENT);
    }
    if (t == T_ - 1) h_last[hoff] = hn;
    // drain all waves' stores, then publish the flag
    __syncthreads();
    if (tid == 0)
      __hip_atomic_store(flags + (size_t)wg * 16, (u32)(t + 1),
                         __ATOMIC_RELAXED, __HIP_MEMORY_SCOPE_AGENT);
  }
}

// ---------------- LN2: out = LN(xn + h_last) fp32 ----------------
__global__ __launch_bounds__(256) void ln2_kernel(const u16* __restrict__ xn,
    const float* __restrict__ h_last, const float* __restrict__ gam,
    const float* __restrict__ bet, float* __restrict__ out) {
  int row = blockIdx.x; int tid = threadIdx.x;
  int bi = row >> 9;
  ushort4v xv = *(const ushort4v*)(xn + (size_t)row * D_ + tid * 4);
  float4 hv = *(const float4*)(h_last + (size_t)bi * D_ + tid * 4);
  float s0 = bf2f(xv.x) + hv.x;
  float s1 = bf2f(xv.y) + hv.y;
  float s2 = bf2f(xv.z) + hv.z;
  float s3 = bf2f(xv.w) + hv.w;
  float s = s0 + s1 + s2 + s3;
  float ss = s0*s0 + s1*s1 + s2*s2 + s3*s3;
  #pragma unroll
  for (int o = 32; o > 0; o >>= 1) { s += __shfl_down(s, o); ss += __shfl_down(ss, o); }
  __shared__ float red[8];
  int w = tid >> 6, l = tid & 63;
  if (l == 0) { red[w] = s; red[4 + w] = ss; }
  __syncthreads();
  s  = red[0] + red[1] + red[2] + red[3];
  ss = red[4] + red[5] + red[6] + red[7];
  float mean = s * (1.f / D_);
  float var  = ss * (1.f / D_) - mean * mean;
  float rstd = rsqrtf(var + 1e-3f);
  float4 g = *(const float4*)(gam + tid * 4);
  float4 b = *(const float4*)(bet + tid * 4);
  float4 o4;
  o4.x = (s0 - mean) * rstd * g.x + b.x;
  o4.y = (s1 - mean) * rstd * g.y + b.y;
  o4.z = (s2 - mean) * rstd * g.z + b.z;
  o4.w = (s3 - mean) * rstd * g.w + b.w;
  *(float4*)(out + (size_t)row * D_ + tid * 4) = o4;
}

extern "C" void kernel_launch(void* const* d_in, const int* in_sizes, int n_in,
                              void* d_out, int out_size, void* d_ws, size_t ws_size,
                              hipStream_t stream) {
  const float* x    = (const float*)d_in[0];
  const float* g1   = (const float*)d_in[1];
  const float* b1   = (const float*)d_in[2];
  const float* Wk   = (const float*)d_in[3];
  const float* Wr   = (const float*)d_in[4];
  const float* bias = (const float*)d_in[5];
  const float* g2   = (const float*)d_in[6];
  const float* b2   = (const float*)d_in[7];
  char* ws = (char*)d_ws;
  u16* xn    = (u16*)(ws + OFF_XN);
  u16* Zx    = (u16*)(ws + OFF_ZX);
  u16* KT    = (u16*)(ws + OFF_KT);
  u16* RT    = (u16*)(ws + OFF_RT);
  u16* hbuf  = (u16*)(ws + OFF_HB);
  u32* flg   = (u32*)(ws + OFF_FLG);
  float* hl  = (float*)(ws + OFF_KT);    // aliases KT (dead after gemm_xk)
  float* out = (float*)d_out;

  init_kernel<<<128, 256, 0, stream>>>((u32*)hbuf, flg);
  ln1_kernel<<<B_ * T_, 256, 0, stream>>>(x, g1, b1, xn);
  transpose_bf16<<<dim3(128, 32), dim3(32, 8), 0, stream>>>(Wk, KT);
  transpose_bf16<<<dim3(128, 32), dim3(32, 8), 0, stream>>>(Wr, RT);
  gemm_xk<<<4096, 256, 0, stream>>>(xn, KT, bias, Zx);
  lstm_scan<<<32, 1024, 0, stream>>>(Zx, RT, hbuf, hl, flg);
  ln2_kernel<<<B_ * T_, 256, 0, stream>>>(xn, hl, g2, b2, out);
}